// Round 5
// baseline (317.076 us; speedup 1.0000x reference)
//
#include <hip/hip_runtime.h>
#include <hip/hip_bf16.h>
#include <cstddef>
#include <cstdint>

// Problem dims (fixed by setup_inputs)
#define NB   32
#define LSEQ 1024
#define HDIM 1280
#define PDIM 128

typedef unsigned short ushort_t;
typedef __bf16 bf16x8 __attribute__((ext_vector_type(8)));
typedef float  f32x4  __attribute__((ext_vector_type(4)));

// ws layout (bytes):
//   [0, 128)    : accb (32 floats)
//   [256, ...)  : wB bf16, MFMA-fragment-packed [kc][t][lane][8]  (kc = K/32)
//   [E_OFF,...) : e bf16 [32768][128]
#define WT_OFF  256
#define E_OFF   (256 + HDIM * PDIM * 2)

__device__ __forceinline__ ushort_t bf16_rne(float x) {
  unsigned u = __float_as_uint(x);
  unsigned r = u + 0x7fffu + ((u >> 16) & 1u);
  return (ushort_t)(r >> 16);
}

// ---------------------------------------------------------------------------
// k0: pack w into MFMA-fragment order (UNCHANGED):
//   wB[((kc*8 + t)*64 + lane)*8 + j] = bf16(w[k][n])
//   with k = kc*32 + lq*8 + j, n = t*16 + lm, lane = lq*16 + lm.
// Block 0 zeroes accb.
// ---------------------------------------------------------------------------
__global__ __launch_bounds__(256) void k0_wt(const float* __restrict__ pw,
                                             ushort_t* __restrict__ wB,
                                             float* __restrict__ wsf) {
  if (blockIdx.x == 0 && threadIdx.x < 64) wsf[threadIdx.x] = 0.0f;
  const int idx = blockIdx.x * 256 + threadIdx.x;
  const int k = idx >> 7, n = idx & 127;
  const int kc = k >> 5, kr = k & 31;
  const int t = n >> 4, lm = n & 15;
  const int lq = kr >> 3, j = kr & 7;
  const int l = lq * 16 + lm;
  wB[((size_t)(kc * 8 + t) * 64 + l) * 8 + j] = bf16_rne(pw[(size_t)k * PDIM + n]);
}

// ---------------------------------------------------------------------------
// k1: e = normalize(hs @ w + b), bf16 out.  BARRIER-FREE main loop.
// (Identical to round-4 submission — that round died on a container infra
// failure before producing any measurement; resubmitting the experiment.)
// 2048 blocks x 256 thr; block = 16 rows; wave w owns K in [w*320, w*320+320)
// (disjoint K-split -> A read exactly once). Each wave is fully autonomous
// for its 10-chunk K-loop: NO barriers, NO LDS until the epilogue combine.
//  - A: global->VGPR dwordx4 x2 per chunk (row lm, k = lq*8), 2-chunk
//    lookahead (BW-paced chunk ~1.25us >> 900cyc HBM latency).
//  - B: fragment-packed wB (1 KB coalesced wave-loads, L2-hot), issued at
//    chunk top BEFORE the A-prefetch so the B-wait (vmcnt~2) leaves the A
//    loads in flight; B-stall is wave-local, hidden by 16 waves/CU TLP.
//  - acc: 8 x f32x4.  VGPR ~110 -> 4 blocks/CU (16 waves, 4/SIMD).
// Epilogue: partials to LDS (132-stride, conflict-light), 1 barrier, wave w
// finalizes rows w*4+lq: sum 4 K-partials + bias, row-norm via 16-lane
// shfl_xor, bf16 store.  D-frag mapping (verified r0/r1): row = lq*4+r,
// col = t*16+lm.
// ---------------------------------------------------------------------------
__global__ __launch_bounds__(256, 4) void k1_mfma(const float* __restrict__ hs,
                                                  const ushort_t* __restrict__ wB,
                                                  const float* __restrict__ pb,
                                                  ushort_t* __restrict__ e) {
  __shared__ float sp[4 * 16 * 132];  // 33792 B -> 4 blocks/CU

  const int tid = threadIdx.x;
  const int l = tid & 63, w = tid >> 6;
  const int lm = l & 15, lq = l >> 4;
  const int m0 = blockIdx.x * 16;

  // A source: row (m0+lm), k-base w*320 + lq*8
  const float* arow = hs + (size_t)(m0 + lm) * HDIM + w * 320 + lq * 8;
  // B fragments: frag (kc = w*10 + c, t) at wB[(kc*8+t)*512 + l*8]
  const ushort_t* bB = wB + (size_t)w * 40960 + (size_t)l * 8;

  f32x4 acc[8];
#pragma unroll
  for (int t = 0; t < 8; ++t) acc[t] = (f32x4){0.f, 0.f, 0.f, 0.f};

  // A staging registers (fully static under unroll; SSA keeps ~2 live)
  f32x4 Ag0[10], Ag1[10];
  Ag0[0] = *(const f32x4*)(arow + 0);
  Ag1[0] = *(const f32x4*)(arow + 4);
  Ag0[1] = *(const f32x4*)(arow + 32);
  Ag1[1] = *(const f32x4*)(arow + 36);

#pragma unroll
  for (int c = 0; c < 10; ++c) {
    // B for this chunk first (so its wait leaves the A-prefetch in flight)
    bf16x8 Bf[8];
#pragma unroll
    for (int t = 0; t < 8; ++t)
      Bf[t] = *(const bf16x8*)(bB + (size_t)c * 4096 + t * 512);

    // A prefetch, 2 chunks ahead
    if (c + 2 < 10) {
      Ag0[c + 2] = *(const f32x4*)(arow + (c + 2) * 32);
      Ag1[c + 2] = *(const f32x4*)(arow + (c + 2) * 32 + 4);
    }

    // cvt current A chunk (waits only the oldest loads)
    const f32x4 f0 = Ag0[c], f1 = Ag1[c];
    union { ushort_t u[8]; bf16x8 v; } cv;
    cv.u[0] = bf16_rne(f0[0]); cv.u[1] = bf16_rne(f0[1]);
    cv.u[2] = bf16_rne(f0[2]); cv.u[3] = bf16_rne(f0[3]);
    cv.u[4] = bf16_rne(f1[0]); cv.u[5] = bf16_rne(f1[1]);
    cv.u[6] = bf16_rne(f1[2]); cv.u[7] = bf16_rne(f1[3]);
    const bf16x8 a = cv.v;

#pragma unroll
    for (int t = 0; t < 8; ++t)
      acc[t] = __builtin_amdgcn_mfma_f32_16x16x32_bf16(a, Bf[t], acc[t], 0, 0, 0);
  }

  // ---- epilogue: K-partial combine + bias + row-norm + bf16 store ----
#pragma unroll
  for (int t = 0; t < 8; ++t)
#pragma unroll
    for (int r = 0; r < 4; ++r)
      sp[(w * 16 + lq * 4 + r) * 132 + t * 16 + lm] = acc[t][r];
  __syncthreads();

  const int row = w * 4 + lq;  // wave w finalizes rows w*4 + lq
  float val[8];
  float s2 = 0.f;
#pragma unroll
  for (int t = 0; t < 8; ++t) {
    const int col = t * 16 + lm;
    val[t] = sp[(0 * 16 + row) * 132 + col] + sp[(1 * 16 + row) * 132 + col] +
             sp[(2 * 16 + row) * 132 + col] + sp[(3 * 16 + row) * 132 + col] +
             pb[col];
    s2 = fmaf(val[t], val[t], s2);
  }
  s2 += __shfl_xor(s2, 1, 64);
  s2 += __shfl_xor(s2, 2, 64);
  s2 += __shfl_xor(s2, 4, 64);
  s2 += __shfl_xor(s2, 8, 64);
  const float inv = 1.0f / sqrtf(s2);
  ushort_t* er = e + (size_t)(m0 + row) * PDIM + lm;
#pragma unroll
  for (int t = 0; t < 8; ++t) er[t * 16] = bf16_rne(val[t] * inv);
}

// ---------------------------------------------------------------------------
// k2: flash-style loss (UNCHANGED — isolating the k1 experiment).
// ---------------------------------------------------------------------------
__global__ __launch_bounds__(256, 3) void k2_loss(const ushort_t* __restrict__ e,
                                                  const int* __restrict__ mask,
                                                  const int* __restrict__ labels,
                                                  float* __restrict__ accb) {
  __shared__ float part[4][32][3];

  const int tid = threadIdx.x;
  const int l = tid & 63, w = tid >> 6;
  const int b  = blockIdx.x >> 5;
  const int i0 = (blockIdx.x & 31) << 5;
  const int lm = l & 15, lq = l >> 4;

  const ushort_t* eb   = e + (size_t)b * LSEQ * PDIM;
  const int*      mrow = mask + b * LSEQ;
  const int*      lrow = labels + b * LSEQ;

  bf16x8 af[2][4];
#pragma unroll
  for (int ii = 0; ii < 2; ++ii) {
    const ushort_t* aptr = eb + (size_t)(i0 + ii * 16 + lm) * PDIM + lq * 8;
#pragma unroll
    for (int c = 0; c < 4; ++c) af[ii][c] = *(const bf16x8*)(aptr + c * 32);
  }

  int  li[2][4], ar[2][4];
  bool vi[2][4];
#pragma unroll
  for (int ii = 0; ii < 2; ++ii)
#pragma unroll
    for (int r = 0; r < 4; ++r) {
      ar[ii][r] = i0 + ii * 16 + lq * 4 + r;
      li[ii][r] = lrow[ar[ii][r]];
      vi[ii][r] = (mrow[ar[ii][r]] != 0) && (li[ii][r] != -100);
    }

  float d[2][4] = {}, ps[2][4] = {}, pc[2][4] = {};
  const float invT = 1.0f / 0.07f;

  // prefetch tile 0
  int jt = w * 16;
  bf16x8 Bc[4];
  int ljc, mjc;
  {
    const int j = jt * 16 + lm;
    const ushort_t* bptr = eb + (size_t)j * PDIM + lq * 8;
#pragma unroll
    for (int c = 0; c < 4; ++c) Bc[c] = *(const bf16x8*)(bptr + c * 32);
    ljc = lrow[j];
    mjc = mrow[j];
  }

#pragma unroll 1
  for (int s = 0; s < 16; ++s, ++jt) {
    bf16x8 Bn[4];
    int ljn = 0, mjn = 0;
    if (s < 15) {
      const int jn = (jt + 1) * 16 + lm;
      const ushort_t* bptr = eb + (size_t)jn * PDIM + lq * 8;
#pragma unroll
      for (int c = 0; c < 4; ++c) Bn[c] = *(const bf16x8*)(bptr + c * 32);
      ljn = lrow[jn];
      mjn = mrow[jn];
    }

    const int j = jt * 16 + lm;
    const bool cvj = (mjc != 0) && (ljc != -100);
#pragma unroll
    for (int ii = 0; ii < 2; ++ii) {
      f32x4 acc = (f32x4){0.f, 0.f, 0.f, 0.f};
#pragma unroll
      for (int c = 0; c < 4; ++c)
        acc = __builtin_amdgcn_mfma_f32_16x16x32_bf16(af[ii][c], Bc[c], acc, 0, 0, 0);
#pragma unroll
      for (int r = 0; r < 4; ++r) {
        const float sv = acc[r] * invT;
        const bool dm  = cvj && (j != ar[ii][r]);
        const float ex = __expf(sv);
        d[ii][r] += dm ? ex : 0.f;
        const bool pos = dm && (ljc == li[ii][r]) && vi[ii][r];
        ps[ii][r] += pos ? sv : 0.f;
        pc[ii][r] += pos ? 1.f : 0.f;
      }
    }

#pragma unroll
    for (int c = 0; c < 4; ++c) Bc[c] = Bn[c];
    ljc = ljn; mjc = mjn;
  }

#pragma unroll
  for (int ii = 0; ii < 2; ++ii)
#pragma unroll
    for (int r = 0; r < 4; ++r) {
#pragma unroll
      for (int off = 1; off < 16; off <<= 1) {
        d[ii][r]  += __shfl_xor(d[ii][r], off, 64);
        ps[ii][r] += __shfl_xor(ps[ii][r], off, 64);
        pc[ii][r] += __shfl_xor(pc[ii][r], off, 64);
      }
    }
  if (lm == 0) {
#pragma unroll
    for (int ii = 0; ii < 2; ++ii)
#pragma unroll
      for (int r = 0; r < 4; ++r) {
        part[w][ii * 16 + lq * 4 + r][0] = d[ii][r];
        part[w][ii * 16 + lq * 4 + r][1] = ps[ii][r];
        part[w][ii * 16 + lq * 4 + r][2] = pc[ii][r];
      }
  }
  __syncthreads();

  if (tid < 32) {
    float D = 0.f, P = 0.f, C = 0.f;
#pragma unroll
    for (int w2 = 0; w2 < 4; ++w2) {
      D += part[w2][tid][0];
      P += part[w2][tid][1];
      C += part[w2][tid][2];
    }
    const float logD = logf(D + 1e-12f);
    float al = (P - C * logD) / (C + 1e-12f);
#pragma unroll
    for (int off = 1; off < 32; off <<= 1) al += __shfl_xor(al, off, 64);
    if (tid == 0) atomicAdd(&accb[b], al);
  }
}

// ---------------------------------------------------------------------------
// k3: final scalar, single block (UNCHANGED).
// ---------------------------------------------------------------------------
__global__ __launch_bounds__(1024) void k3_final(const int* __restrict__ mask,
                                                 const int* __restrict__ labels,
                                                 const float* __restrict__ accb,
                                                 float* __restrict__ out) {
  __shared__ float lossv[NB];
  __shared__ float okv[NB];
  const int t = threadIdx.x;
  const int b = t >> 5, sub = t & 31;

  int cm = 0, cv = 0;
#pragma unroll
  for (int q = 0; q < 8; ++q) {
    const int idx = b * LSEQ + q * 128 + sub * 4;
    const int4 mv = *(const int4*)(mask + idx);
    const int4 lv = *(const int4*)(labels + idx);
    cm += mv.x + mv.y + mv.z + mv.w;
    cv += ((mv.x != 0 && lv.x != -100) ? 1 : 0) +
          ((mv.y != 0 && lv.y != -100) ? 1 : 0) +
          ((mv.z != 0 && lv.z != -100) ? 1 : 0) +
          ((mv.w != 0 && lv.w != -100) ? 1 : 0);
  }
#pragma unroll
  for (int off = 16; off; off >>= 1) {
    cm += __shfl_xor(cm, off, 64);
    cv += __shfl_xor(cv, off, 64);
  }
  if (sub == 0) {
    const bool ok = (cm >= 2);
    lossv[b] = ok ? (-accb[b] / fmaxf((float)cv, 1.0f)) : 0.0f;
    okv[b]   = ok ? 1.0f : 0.0f;
  }
  __syncthreads();
  if (t < NB) {
    float lv = lossv[t], ov = okv[t];
#pragma unroll
    for (int off = 16; off; off >>= 1) {
      lv += __shfl_xor(lv, off, 64);
      ov += __shfl_xor(ov, off, 64);
    }
    if (t == 0) out[0] = lv / fmaxf(ov, 1.0f);
  }
}

// ---------------------------------------------------------------------------
extern "C" void kernel_launch(void* const* d_in, const int* in_sizes, int n_in,
                              void* d_out, int out_size, void* d_ws, size_t ws_size,
                              hipStream_t stream) {
  (void)in_sizes; (void)n_in; (void)out_size; (void)ws_size;
  const float* hs     = (const float*)d_in[0];
  const float* pw     = (const float*)d_in[1];
  const float* pb     = (const float*)d_in[2];
  const int*   mask   = (const int*)d_in[3];
  const int*   labels = (const int*)d_in[4];
  float* out = (float*)d_out;

  char* wsb = (char*)d_ws;
  float*    wsf  = (float*)wsb;
  float*    accb = wsf;  // floats [0,32)
  ushort_t* wB   = (ushort_t*)(wsb + WT_OFF);
  ushort_t* e    = (ushort_t*)(wsb + E_OFF);

  k0_wt<<<(HDIM * PDIM) / 256, 256, 0, stream>>>(pw, wB, wsf);
  k1_mfma<<<(NB * LSEQ) / 16, 256, 0, stream>>>(hs, wB, pb, e);
  k2_loss<<<NB * 32, 256, 0, stream>>>(e, mask, labels, accb);
  k3_final<<<1, 1024, 0, stream>>>(mask, labels, accb, out);
}

// Round 6
// 294.460 us; speedup vs baseline: 1.0768x; 1.0768x over previous
//
#include <hip/hip_runtime.h>
#include <hip/hip_bf16.h>
#include <cstddef>
#include <cstdint>

// Problem dims (fixed by setup_inputs)
#define NB   32
#define LSEQ 1024
#define HDIM 1280
#define PDIM 128
#define KSTEPS 20  // HDIM / 64

typedef unsigned short ushort_t;
typedef __bf16 bf16x8 __attribute__((ext_vector_type(8)));
typedef float  f32x4  __attribute__((ext_vector_type(4)));

// ws layout (bytes):
//   [0, 128)    : accb (32 floats)
//   [256, ...)  : wB bf16, MFMA-fragment-packed [kc][t][lane][8]  (kc = K/32)
//   [E_OFF,...) : e bf16 [32768][128]
#define WT_OFF  256
#define E_OFF   (256 + HDIM * PDIM * 2)

__device__ __forceinline__ ushort_t bf16_rne(float x) {
  unsigned u = __float_as_uint(x);
  unsigned r = u + 0x7fffu + ((u >> 16) & 1u);
  return (ushort_t)(r >> 16);
}

// global -> LDS direct copy, 16 B per lane (lane l lands at base + l*16)
#define GLD_LDS16(gp, lp)                                                      \
  __builtin_amdgcn_global_load_lds(                                            \
      (const __attribute__((address_space(1))) void*)(gp),                     \
      (__attribute__((address_space(3))) void*)(lp), 16, 0, 0)

// fused counted wait + barrier: the ONLY wait in the k1 main loop
#define WAIT_BAR(N)                                                            \
  asm volatile("s_waitcnt vmcnt(" #N ") lgkmcnt(0)\n\ts_barrier" ::: "memory")

// ---------------------------------------------------------------------------
// k0: pack w into MFMA-fragment order (UNCHANGED):
//   wB[((kc*8 + t)*64 + lane)*8 + j] = bf16(w[k][n])
//   with k = kc*32 + lq*8 + j, n = t*16 + lm, lane = lq*16 + lm.
// Block 0 zeroes accb.
// ---------------------------------------------------------------------------
__global__ __launch_bounds__(256) void k0_wt(const float* __restrict__ pw,
                                             ushort_t* __restrict__ wB,
                                             float* __restrict__ wsf) {
  if (blockIdx.x == 0 && threadIdx.x < 64) wsf[threadIdx.x] = 0.0f;
  const int idx = blockIdx.x * 256 + threadIdx.x;
  const int k = idx >> 7, n = idx & 127;
  const int kc = k >> 5, kr = k & 31;
  const int t = n >> 4, lm = n & 15;
  const int lq = kr >> 3, j = kr & 7;
  const int l = lq * 16 + lm;
  wB[((size_t)(kc * 8 + t) * 64 + l) * 8 + j] = bf16_rne(pw[(size_t)k * PDIM + n]);
}

// ---------------------------------------------------------------------------
// k1: e = normalize(hs @ w + b), bf16 out.  TRUE counted-vmcnt pipeline:
// the main loop contains ZERO register-destination VMEM loads (A and B both
// staged via global_load_lds), so the compiler cannot insert its own vmcnt
// drains (the r0/r3/r5 failure mode: reg-prefetch demoted / Bn-copy waits).
// Block 256 thr, BM=32, BK=64, 20 steps; 3 x 24 KB LDS buffers (72 KB ->
// 2 blocks/CU). Per step per thread: 2 A-loads + 4 B-loads = 6 wave-loads
// per wave. One fused {s_waitcnt vmcnt(6) lgkmcnt(0); s_barrier} per step
// (vmcnt(0) only at the final step): stage s+1 stays in flight across the
// barrier; stage s+2 is issued right after it.
//  - A LDS layout: plane0 = 32 rows x 128 B (k-chunks 0..7), plane1 at
//    +4096 (chunks 8..15); thread tid stages row tid>>3, chunk tid&7.
//  - B: per step a PURE LINEAR 16 KB copy of wB block s (k0's fragment
//    packing IS the fragment layout): fragment (kh, t) at +8192 +
//    (kh*8+t)*1024 + l*16 -> conflict-free 1 KB wave ds_reads.
// Epilogue: r3's verified cross-wave row-norm (sp aliases buf0 first 512 B;
// buf0's last use is step 18, all waves past step-19's barrier). D-frag
// mapping (verified r0-r5): row = m*16+lq*4+r, col = w*32+tt*16+lm.
// ---------------------------------------------------------------------------
__global__ __launch_bounds__(256, 2) void k1_mfma(const float* __restrict__ hs,
                                                  const ushort_t* __restrict__ wB,
                                                  const float* __restrict__ pb,
                                                  ushort_t* __restrict__ e) {
  __shared__ __align__(16) char smem[3][24576];

  const int tid = threadIdx.x;
  const int l = tid & 63, w = tid >> 6;
  const int lm = l & 15, lq = l >> 4;
  const int m0 = blockIdx.x * 32;

  // staging sources
  const int ar = tid >> 3, ac = tid & 7;  // A: row 0..31, 16B-chunk 0..7
  const float* aS = hs + (size_t)(m0 + ar) * HDIM + ac * 4;
  const char*  bS = (const char*)wB + tid * 16;

#define STAGE(ss, buf)                                                         \
  do {                                                                         \
    GLD_LDS16(aS + (ss) * 64,      (buf) + tid * 16);                          \
    GLD_LDS16(aS + (ss) * 64 + 32, (buf) + 4096 + tid * 16);                   \
    GLD_LDS16(bS + (size_t)(ss) * 16384,         (buf) + 8192  + tid * 16);    \
    GLD_LDS16(bS + (size_t)(ss) * 16384 + 4096,  (buf) + 12288 + tid * 16);    \
    GLD_LDS16(bS + (size_t)(ss) * 16384 + 8192,  (buf) + 16384 + tid * 16);    \
    GLD_LDS16(bS + (size_t)(ss) * 16384 + 12288, (buf) + 20480 + tid * 16);    \
  } while (0)

  f32x4 acc[2][2];
#pragma unroll
  for (int m = 0; m < 2; ++m)
#pragma unroll
    for (int tt = 0; tt < 2; ++tt) acc[m][tt] = (f32x4){0.f, 0.f, 0.f, 0.f};

  // prologue: stage steps 0 and 1
  char* p0 = smem[0];
  char* p1 = smem[1];
  char* p2 = smem[2];
  STAGE(0, p0);
  STAGE(1, p1);

#pragma unroll 1
  for (int s = 0; s < KSTEPS; ++s) {
    // stage(s) complete; stage(s+1) (6 wave-loads) stays in flight
    if (s < KSTEPS - 1) WAIT_BAR(6);
    else                WAIT_BAR(0);

    // stage step s+2 into the buffer whose readers finished at step s-1
    // (guaranteed by the barrier above: lgkmcnt(0) + s_barrier)
    if (s + 2 < KSTEPS) STAGE(s + 2, p2);

    // A fragments from LDS + f32->bf16 cvt (bitwise-identical numerics)
    bf16x8 a[2][2];
#pragma unroll
    for (int m = 0; m < 2; ++m)
#pragma unroll
      for (int kh = 0; kh < 2; ++kh) {
        const char* base = p0 + kh * 4096 + (m * 16 + lm) * 128 + lq * 32;
        const f32x4 f0 = *(const f32x4*)base;
        const f32x4 f1 = *(const f32x4*)(base + 16);
        union { ushort_t u[8]; bf16x8 v; } cv;
        cv.u[0] = bf16_rne(f0[0]); cv.u[1] = bf16_rne(f0[1]);
        cv.u[2] = bf16_rne(f0[2]); cv.u[3] = bf16_rne(f0[3]);
        cv.u[4] = bf16_rne(f1[0]); cv.u[5] = bf16_rne(f1[1]);
        cv.u[6] = bf16_rne(f1[2]); cv.u[7] = bf16_rne(f1[3]);
        a[m][kh] = cv.v;
      }

    // B fragments: conflict-free contiguous 1 KB wave-reads
    bf16x8 Bf[2][2];
#pragma unroll
    for (int kh = 0; kh < 2; ++kh)
#pragma unroll
      for (int tt = 0; tt < 2; ++tt)
        Bf[tt][kh] = *(const bf16x8*)(p0 + 8192 +
                                      ((kh * 8 + w * 2 + tt) * 64 + l) * 16);

#pragma unroll
    for (int m = 0; m < 2; ++m)
#pragma unroll
      for (int tt = 0; tt < 2; ++tt)
#pragma unroll
        for (int kh = 0; kh < 2; ++kh)
          acc[m][tt] = __builtin_amdgcn_mfma_f32_16x16x32_bf16(
              a[m][kh], Bf[tt][kh], acc[m][tt], 0, 0, 0);

    // rotate buffers
    char* tmp = p0; p0 = p1; p1 = p2; p2 = tmp;
  }
#undef STAGE

  // ---- epilogue: bias, cross-wave row-norm, bf16 store (r3-verified) ----
  const float pbv0 = pb[w * 32 + lm];
  const float pbv1 = pb[w * 32 + 16 + lm];
#pragma unroll
  for (int m = 0; m < 2; ++m)
#pragma unroll
    for (int r = 0; r < 4; ++r) {
      acc[m][0][r] += pbv0;
      acc[m][1][r] += pbv1;
    }

  // sp aliases smem[0][0:512): last read of buf0 was step 18 (done before
  // step 19's barrier); step-19 readers use smem[1] (disjoint).
  float* sp = (float*)smem;  // [4 waves][32 rows] partial sums of squares
#pragma unroll
  for (int m = 0; m < 2; ++m)
#pragma unroll
    for (int r = 0; r < 4; ++r) {
      float s2 = acc[m][0][r] * acc[m][0][r] + acc[m][1][r] * acc[m][1][r];
      s2 += __shfl_xor(s2, 1, 64);
      s2 += __shfl_xor(s2, 2, 64);
      s2 += __shfl_xor(s2, 4, 64);
      s2 += __shfl_xor(s2, 8, 64);
      if (lm == 0) sp[w * 32 + m * 16 + lq * 4 + r] = s2;
    }
  __syncthreads();

#pragma unroll
  for (int m = 0; m < 2; ++m)
#pragma unroll
    for (int r = 0; r < 4; ++r) {
      const int row = m * 16 + lq * 4 + r;
      const float tot = sp[row] + sp[32 + row] + sp[64 + row] + sp[96 + row];
      const float inv = 1.0f / sqrtf(tot);
      ushort_t* er = e + (size_t)(m0 + row) * PDIM + w * 32 + lm;
      er[0]  = bf16_rne(acc[m][0][r] * inv);
      er[16] = bf16_rne(acc[m][1][r] * inv);
    }
}

// ---------------------------------------------------------------------------
// k2: flash-style loss (UNCHANGED — isolating the k1 experiment).
// ---------------------------------------------------------------------------
__global__ __launch_bounds__(256, 3) void k2_loss(const ushort_t* __restrict__ e,
                                                  const int* __restrict__ mask,
                                                  const int* __restrict__ labels,
                                                  float* __restrict__ accb) {
  __shared__ float part[4][32][3];

  const int tid = threadIdx.x;
  const int l = tid & 63, w = tid >> 6;
  const int b  = blockIdx.x >> 5;
  const int i0 = (blockIdx.x & 31) << 5;
  const int lm = l & 15, lq = l >> 4;

  const ushort_t* eb   = e + (size_t)b * LSEQ * PDIM;
  const int*      mrow = mask + b * LSEQ;
  const int*      lrow = labels + b * LSEQ;

  bf16x8 af[2][4];
#pragma unroll
  for (int ii = 0; ii < 2; ++ii) {
    const ushort_t* aptr = eb + (size_t)(i0 + ii * 16 + lm) * PDIM + lq * 8;
#pragma unroll
    for (int c = 0; c < 4; ++c) af[ii][c] = *(const bf16x8*)(aptr + c * 32);
  }

  int  li[2][4], ar[2][4];
  bool vi[2][4];
#pragma unroll
  for (int ii = 0; ii < 2; ++ii)
#pragma unroll
    for (int r = 0; r < 4; ++r) {
      ar[ii][r] = i0 + ii * 16 + lq * 4 + r;
      li[ii][r] = lrow[ar[ii][r]];
      vi[ii][r] = (mrow[ar[ii][r]] != 0) && (li[ii][r] != -100);
    }

  float d[2][4] = {}, ps[2][4] = {}, pc[2][4] = {};
  const float invT = 1.0f / 0.07f;

  // prefetch tile 0
  int jt = w * 16;
  bf16x8 Bc[4];
  int ljc, mjc;
  {
    const int j = jt * 16 + lm;
    const ushort_t* bptr = eb + (size_t)j * PDIM + lq * 8;
#pragma unroll
    for (int c = 0; c < 4; ++c) Bc[c] = *(const bf16x8*)(bptr + c * 32);
    ljc = lrow[j];
    mjc = mrow[j];
  }

#pragma unroll 1
  for (int s = 0; s < 16; ++s, ++jt) {
    bf16x8 Bn[4];
    int ljn = 0, mjn = 0;
    if (s < 15) {
      const int jn = (jt + 1) * 16 + lm;
      const ushort_t* bptr = eb + (size_t)jn * PDIM + lq * 8;
#pragma unroll
      for (int c = 0; c < 4; ++c) Bn[c] = *(const bf16x8*)(bptr + c * 32);
      ljn = lrow[jn];
      mjn = mrow[jn];
    }

    const int j = jt * 16 + lm;
    const bool cvj = (mjc != 0) && (ljc != -100);
#pragma unroll
    for (int ii = 0; ii < 2; ++ii) {
      f32x4 acc = (f32x4){0.f, 0.f, 0.f, 0.f};
#pragma unroll
      for (int c = 0; c < 4; ++c)
        acc = __builtin_amdgcn_mfma_f32_16x16x32_bf16(af[ii][c], Bc[c], acc, 0, 0, 0);
#pragma unroll
      for (int r = 0; r < 4; ++r) {
        const float sv = acc[r] * invT;
        const bool dm  = cvj && (j != ar[ii][r]);
        const float ex = __expf(sv);
        d[ii][r] += dm ? ex : 0.f;
        const bool pos = dm && (ljc == li[ii][r]) && vi[ii][r];
        ps[ii][r] += pos ? sv : 0.f;
        pc[ii][r] += pos ? 1.f : 0.f;
      }
    }

#pragma unroll
    for (int c = 0; c < 4; ++c) Bc[c] = Bn[c];
    ljc = ljn; mjc = mjn;
  }

#pragma unroll
  for (int ii = 0; ii < 2; ++ii)
#pragma unroll
    for (int r = 0; r < 4; ++r) {
#pragma unroll
      for (int off = 1; off < 16; off <<= 1) {
        d[ii][r]  += __shfl_xor(d[ii][r], off, 64);
        ps[ii][r] += __shfl_xor(ps[ii][r], off, 64);
        pc[ii][r] += __shfl_xor(pc[ii][r], off, 64);
      }
    }
  if (lm == 0) {
#pragma unroll
    for (int ii = 0; ii < 2; ++ii)
#pragma unroll
      for (int r = 0; r < 4; ++r) {
        part[w][ii * 16 + lq * 4 + r][0] = d[ii][r];
        part[w][ii * 16 + lq * 4 + r][1] = ps[ii][r];
        part[w][ii * 16 + lq * 4 + r][2] = pc[ii][r];
      }
  }
  __syncthreads();

  if (tid < 32) {
    float D = 0.f, P = 0.f, C = 0.f;
#pragma unroll
    for (int w2 = 0; w2 < 4; ++w2) {
      D += part[w2][tid][0];
      P += part[w2][tid][1];
      C += part[w2][tid][2];
    }
    const float logD = logf(D + 1e-12f);
    float al = (P - C * logD) / (C + 1e-12f);
#pragma unroll
    for (int off = 1; off < 32; off <<= 1) al += __shfl_xor(al, off, 64);
    if (tid == 0) atomicAdd(&accb[b], al);
  }
}

// ---------------------------------------------------------------------------
// k3: final scalar, single block (UNCHANGED).
// ---------------------------------------------------------------------------
__global__ __launch_bounds__(1024) void k3_final(const int* __restrict__ mask,
                                                 const int* __restrict__ labels,
                                                 const float* __restrict__ accb,
                                                 float* __restrict__ out) {
  __shared__ float lossv[NB];
  __shared__ float okv[NB];
  const int t = threadIdx.x;
  const int b = t >> 5, sub = t & 31;

  int cm = 0, cv = 0;
#pragma unroll
  for (int q = 0; q < 8; ++q) {
    const int idx = b * LSEQ + q * 128 + sub * 4;
    const int4 mv = *(const int4*)(mask + idx);
    const int4 lv = *(const int4*)(labels + idx);
    cm += mv.x + mv.y + mv.z + mv.w;
    cv += ((mv.x != 0 && lv.x != -100) ? 1 : 0) +
          ((mv.y != 0 && lv.y != -100) ? 1 : 0) +
          ((mv.z != 0 && lv.z != -100) ? 1 : 0) +
          ((mv.w != 0 && lv.w != -100) ? 1 : 0);
  }
#pragma unroll
  for (int off = 16; off; off >>= 1) {
    cm += __shfl_xor(cm, off, 64);
    cv += __shfl_xor(cv, off, 64);
  }
  if (sub == 0) {
    const bool ok = (cm >= 2);
    lossv[b] = ok ? (-accb[b] / fmaxf((float)cv, 1.0f)) : 0.0f;
    okv[b]   = ok ? 1.0f : 0.0f;
  }
  __syncthreads();
  if (t < NB) {
    float lv = lossv[t], ov = okv[t];
#pragma unroll
    for (int off = 16; off; off >>= 1) {
      lv += __shfl_xor(lv, off, 64);
      ov += __shfl_xor(ov, off, 64);
    }
    if (t == 0) out[0] = lv / fmaxf(ov, 1.0f);
  }
}

// ---------------------------------------------------------------------------
extern "C" void kernel_launch(void* const* d_in, const int* in_sizes, int n_in,
                              void* d_out, int out_size, void* d_ws, size_t ws_size,
                              hipStream_t stream) {
  (void)in_sizes; (void)n_in; (void)out_size; (void)ws_size;
  const float* hs     = (const float*)d_in[0];
  const float* pw     = (const float*)d_in[1];
  const float* pb     = (const float*)d_in[2];
  const int*   mask   = (const int*)d_in[3];
  const int*   labels = (const int*)d_in[4];
  float* out = (float*)d_out;

  char* wsb = (char*)d_ws;
  float*    wsf  = (float*)wsb;
  float*    accb = wsf;  // floats [0,32)
  ushort_t* wB   = (ushort_t*)(wsb + WT_OFF);
  ushort_t* e    = (ushort_t*)(wsb + E_OFF);

  k0_wt<<<(HDIM * PDIM) / 256, 256, 0, stream>>>(pw, wB, wsf);
  k1_mfma<<<(NB * LSEQ) / 32, 256, 0, stream>>>(hs, wB, pb, e);
  k2_loss<<<NB * 32, 256, 0, stream>>>(e, mask, labels, accb);
  k3_final<<<1, 1024, 0, stream>>>(mask, labels, accb, out);
}